// Round 4
// baseline (9.822 us; speedup 1.0000x reference)
//
#include <hip/hip_runtime.h>
#include <stdint.h>

#define NN 50000
#define NE 800000
#define NBLK 196   // ceil(NN/256)

typedef float f32x4 __attribute__((ext_vector_type(4)));
typedef short s16x8 __attribute__((ext_vector_type(8)));

__device__ __forceinline__ float bf2f(unsigned short u) {
    union { unsigned int i; float f; } v; v.i = ((unsigned int)u) << 16; return v.f;
}
__device__ __forceinline__ unsigned short f2bf(float x) {
    union { float f; unsigned int i; } v; v.f = x;
    unsigned int r = v.i + 0x7FFFu + ((v.i >> 16) & 1u);
    return (unsigned short)(r >> 16);
}

// ---------------- graph preprocessing ----------------

__global__ void k_deg(const int* __restrict__ src, const int* __restrict__ dst,
                      int* __restrict__ dego, int* __restrict__ degi) {
    int e = blockIdx.x * 256 + threadIdx.x;
    if (e < NE) {
        atomicAdd(&dego[src[e]], 1);
        atomicAdd(&degi[dst[e]], 1);
    }
}

__global__ void k_norm(const int* __restrict__ dego, const int* __restrict__ degi,
                       float* __restrict__ ns, float* __restrict__ nd) {
    int i = blockIdx.x * 256 + threadIdx.x;
    if (i < NN) {
        ns[i] = dego[i] > 0 ? rsqrtf((float)dego[i]) : 0.f;
        nd[i] = degi[i] > 0 ? rsqrtf((float)degi[i]) : 0.f;
    }
}

// parallel exclusive scan of deg_i -> row_ptr, cursor (3 phases)
__global__ void k_scanA(const int* __restrict__ deg, int* __restrict__ incl,
                        int* __restrict__ bsum) {
    __shared__ int sm[256];
    int t = threadIdx.x, i = blockIdx.x * 256 + t;
    int v = (i < NN) ? deg[i] : 0;
    sm[t] = v;
    __syncthreads();
#pragma unroll
    for (int off = 1; off < 256; off <<= 1) {
        int tv = (t >= off) ? sm[t - off] : 0;
        __syncthreads();
        sm[t] += tv;
        __syncthreads();
    }
    if (i < NN) incl[i] = sm[t];
    if (t == 255) bsum[blockIdx.x] = sm[255];
}

__global__ void k_scanB(const int* __restrict__ bsum, int* __restrict__ boff,
                        int* __restrict__ row_ptr) {
    __shared__ int sm[256];
    int t = threadIdx.x;
    int v = (t < NBLK) ? bsum[t] : 0;
    sm[t] = v;
    __syncthreads();
#pragma unroll
    for (int off = 1; off < 256; off <<= 1) {
        int tv = (t >= off) ? sm[t - off] : 0;
        __syncthreads();
        sm[t] += tv;
        __syncthreads();
    }
    if (t < NBLK) boff[t] = sm[t] - v;  // exclusive
    if (t == 255) row_ptr[NN] = sm[255];
}

__global__ void k_scanC(const int* __restrict__ deg, const int* __restrict__ incl,
                        const int* __restrict__ boff, int* __restrict__ row_ptr,
                        int* __restrict__ cursor) {
    int i = blockIdx.x * 256 + threadIdx.x;
    if (i < NN) {
        int ex = boff[blockIdx.x] + incl[i] - deg[i];
        row_ptr[i] = ex;
        cursor[i] = ex;
    }
}

// fill CSR columns; also emit per-edge weight ewt = ns[src] (contiguous for prop)
__global__ void k_fill(const int* __restrict__ src, const int* __restrict__ dst,
                       const float* __restrict__ ns,
                       int* __restrict__ cursor, int* __restrict__ col_src,
                       float* __restrict__ ewt) {
    int e = blockIdx.x * 256 + threadIdx.x;
    if (e < NE) {
        int s = src[e];
        int slot = atomicAdd(&cursor[dst[e]], 1);
        col_src[slot] = s;
        ewt[slot] = ns[s];
    }
}

// ---------------- weight prep ----------------
// W [K,Ncols] fp32 row-major -> Wt hi/lo [Ncols,K] bf16 (B^T layout)
__global__ void k_wsplit(const float* __restrict__ W, unsigned short* __restrict__ hi,
                         unsigned short* __restrict__ lo, int K, int Ncols) {
    int idx = blockIdx.x * 256 + threadIdx.x;
    if (idx < K * Ncols) {
        int n = idx / K, k = idx - n * K;
        float w = W[(size_t)k * Ncols + n];
        unsigned short h = f2bf(w);
        hi[idx] = h;
        lo[idx] = f2bf(w - bf2f(h));
    }
}

struct QkvPtrs {
    const float* w[9];          // [layer*3 + which], each [256,256]
    unsigned short* h[3];       // merged [768][256] per layer
    unsigned short* l[3];
};

__global__ void k_wsplit9(QkvPtrs P) {
    int m = blockIdx.y;               // 0..8
    int layer = m / 3, which = m - layer * 3;
    int idx = blockIdx.x * 256 + threadIdx.x;   // 0..65535
    int n = idx >> 8, k = idx & 255;
    float w = P.w[m][(size_t)k * 256 + n];
    unsigned short h = f2bf(w);
    size_t o = (size_t)(which * 256 + n) * 256 + k;
    P.h[layer][o] = h;
    P.l[layer][o] = f2bf(w - bf2f(h));
}

struct BiasPtrs { const float* b[9]; float* dst; };  // dst [3][768]

__global__ void k_bcat(BiasPtrs P) {
    int m = blockIdx.x;               // 0..8
    int layer = m / 3, which = m - layer * 3;
    int t = threadIdx.x;              // 0..255
    P.dst[layer * 768 + which * 256 + t] = P.b[m][t];
}

// ---------------- GCN propagate: y[d] = nd[d] * sum_{e:dst=d} ewt[e] * x[src[e]] ----------------
// One wave per node; lane owns 4 consecutive cols. Next src index prefetched.

__global__ void k_prop(const float* __restrict__ x, int ldx,
                       const int* __restrict__ row_ptr, const int* __restrict__ col_src,
                       const float* __restrict__ ewt, const float* __restrict__ ndv,
                       float* __restrict__ y) {
    int w = (int)((blockIdx.x * 256 + threadIdx.x) >> 6);
    if (w >= NN) return;
    int lane = threadIdx.x & 63;
    int c = lane * 4;
    float a0 = 0, a1 = 0, a2 = 0, a3 = 0;
    int e0 = row_ptr[w], e1 = row_ptr[w + 1];
    int sv = (e0 < e1) ? col_src[e0] : 0;
    for (int p = e0; p < e1; ++p) {
        int sn = (p + 1 < e1) ? col_src[p + 1] : 0;
        float wv = ewt[p];
        const float4 xv = *(const float4*)(x + (size_t)sv * ldx + c);
        a0 += wv * xv.x; a1 += wv * xv.y; a2 += wv * xv.z; a3 += wv * xv.w;
        sv = sn;
    }
    float sc = ndv[w];
    float4 o; o.x = a0 * sc; o.y = a1 * sc; o.z = a2 * sc; o.w = a3 * sc;
    *(float4*)(y + (size_t)w * 256 + c) = o;
}

// ---------------- edge attention ----------------
// Q [NN,256] fp32; KV [NN,512] bf16 (cols 0-255 K, 256-511 V). One wave per dst.
// 16-lane group g = head g; lane covers 4 dims. Next src index prefetched.

__global__ void k_attn(const float* __restrict__ Qbuf, const unsigned short* __restrict__ KV,
                       const int* __restrict__ row_ptr, const int* __restrict__ col_src,
                       float* __restrict__ xo) {
    int w = (int)((blockIdx.x * 256 + threadIdx.x) >> 6);
    if (w >= NN) return;
    int lane = threadIdx.x & 63;
    int c = lane * 4;
    const float4 q = *(const float4*)(Qbuf + (size_t)w * 256 + c);
    float v0 = 0, v1 = 0, v2 = 0, v3 = 0, z = 0;
    int e0 = row_ptr[w], e1 = row_ptr[w + 1];
    int sv = (e0 < e1) ? col_src[e0] : 0;
    for (int p = e0; p < e1; ++p) {
        int sn = (p + 1 < e1) ? col_src[p + 1] : 0;
        const ushort4 ku = *(const ushort4*)(KV + (size_t)sv * 512 + c);
        const ushort4 vu = *(const ushort4*)(KV + (size_t)sv * 512 + 256 + c);
        float t = q.x * bf2f(ku.x) + q.y * bf2f(ku.y) + q.z * bf2f(ku.z) + q.w * bf2f(ku.w);
        t += __shfl_xor(t, 1);
        t += __shfl_xor(t, 2);
        t += __shfl_xor(t, 4);
        t += __shfl_xor(t, 8);
        float scv = __expf(fminf(fmaxf(t * 0.125f, -10.f), 10.f));
        v0 += scv * bf2f(vu.x); v1 += scv * bf2f(vu.y);
        v2 += scv * bf2f(vu.z); v3 += scv * bf2f(vu.w);
        z += scv;
        sv = sn;
    }
    float inv = 1.f / (z + 1e-6f);
    float4 o; o.x = v0 * inv; o.y = v1 * inv; o.z = v2 * inv; o.w = v3 * inv;
    *(float4*)(xo + (size_t)w * 768 + c) = o;
}

// ---------------- split-bf16 GEMM: C = relu(A @ W + b) ----------------
// A: fp32 [M,K] (lda), split to hi/lo bf16 in registers during LDS staging.
// B: hi/lo bf16 B^T [Ncols,K]. 3-term MFMA (hh + hl + lh) ~ fp32 accuracy.
// 128x128 tile, BK=32, 4 waves (2x2 of 64x64), mfma_f32_16x16x32_bf16.
// MODE 0: fp32 C at ldc/coff. MODE 1: cols 0-255 -> Qf fp32 [M,256],
//         cols 256-767 -> KVb bf16 [M,512].

template <int MODE>
__global__ __launch_bounds__(256) void k_gemm(
    const float* __restrict__ A, int lda,
    const unsigned short* __restrict__ Bhi, const unsigned short* __restrict__ Blo,
    const float* __restrict__ bias,
    float* __restrict__ C, unsigned short* __restrict__ KVb,
    int ldc, int coff, int M, int K) {
    __shared__ unsigned short sA[2][128][40];
    __shared__ unsigned short sB[2][128][40];
    const int tid = threadIdx.x;
    const int lane = tid & 63;
    const int wid = tid >> 6;
    const int wm = wid & 1, wn = wid >> 1;
    const int fr = lane & 15, kg = lane >> 4;
    const int brow = blockIdx.x * 128;
    const int bcol = blockIdx.y * 128;
    f32x4 acc[4][4] = {};

    for (int k0 = 0; k0 < K; k0 += 32) {
#pragma unroll
        for (int rep = 0; rep < 2; ++rep) {
            int s = tid + rep * 256;
            int row = s >> 2, ks = (s & 3) * 8;
            int gr = brow + row;
            float4 f0 = make_float4(0, 0, 0, 0), f1 = make_float4(0, 0, 0, 0);
            if (gr < M) {
                const float4* ap = (const float4*)(A + (size_t)gr * lda + k0 + ks);
                f0 = ap[0];
                f1 = ap[1];
            }
            ushort4 h0, h1v, l0, l1v;
            h0.x = f2bf(f0.x); l0.x = f2bf(f0.x - bf2f(h0.x));
            h0.y = f2bf(f0.y); l0.y = f2bf(f0.y - bf2f(h0.y));
            h0.z = f2bf(f0.z); l0.z = f2bf(f0.z - bf2f(h0.z));
            h0.w = f2bf(f0.w); l0.w = f2bf(f0.w - bf2f(h0.w));
            h1v.x = f2bf(f1.x); l1v.x = f2bf(f1.x - bf2f(h1v.x));
            h1v.y = f2bf(f1.y); l1v.y = f2bf(f1.y - bf2f(h1v.y));
            h1v.z = f2bf(f1.z); l1v.z = f2bf(f1.z - bf2f(h1v.z));
            h1v.w = f2bf(f1.w); l1v.w = f2bf(f1.w - bf2f(h1v.w));
            *(ushort4*)&sA[0][row][ks] = h0;
            *(ushort4*)&sA[0][row][ks + 4] = h1v;
            *(ushort4*)&sA[1][row][ks] = l0;
            *(ushort4*)&sA[1][row][ks + 4] = l1v;
            size_t bbase = (size_t)(bcol + row) * K + k0 + ks;
            *(uint4*)&sB[0][row][ks] = *(const uint4*)(Bhi + bbase);
            *(uint4*)&sB[1][row][ks] = *(const uint4*)(Blo + bbase);
        }
        __syncthreads();
        s16x8 ah[4], al[4], bh[4], bl[4];
#pragma unroll
        for (int f = 0; f < 4; ++f) {
            ah[f] = *(const s16x8*)&sA[0][wm * 64 + f * 16 + fr][kg * 8];
            al[f] = *(const s16x8*)&sA[1][wm * 64 + f * 16 + fr][kg * 8];
            bh[f] = *(const s16x8*)&sB[0][wn * 64 + f * 16 + fr][kg * 8];
            bl[f] = *(const s16x8*)&sB[1][wn * 64 + f * 16 + fr][kg * 8];
        }
#pragma unroll
        for (int i = 0; i < 4; ++i)
#pragma unroll
            for (int j = 0; j < 4; ++j) {
                acc[i][j] = __builtin_amdgcn_mfma_f32_16x16x32_bf16(ah[i], bh[j], acc[i][j], 0, 0, 0);
                acc[i][j] = __builtin_amdgcn_mfma_f32_16x16x32_bf16(ah[i], bl[j], acc[i][j], 0, 0, 0);
                acc[i][j] = __builtin_amdgcn_mfma_f32_16x16x32_bf16(al[i], bh[j], acc[i][j], 0, 0, 0);
            }
        __syncthreads();
    }

#pragma unroll
    for (int i = 0; i < 4; ++i) {
#pragma unroll
        for (int j = 0; j < 4; ++j) {
            int colG = bcol + wn * 64 + j * 16 + fr;
            float bb = bias[colG];
#pragma unroll
            for (int r = 0; r < 4; ++r) {
                int row = brow + wm * 64 + i * 16 + kg * 4 + r;
                if (row < M) {
                    float v = fmaxf(acc[i][j][r] + bb, 0.f);
                    if (MODE == 0) {
                        C[(size_t)row * ldc + coff + colG] = v;
                    } else {
                        if (colG < 256) C[(size_t)row * 256 + colG] = v;
                        else KVb[(size_t)row * 512 + (colG - 256)] = f2bf(v);
                    }
                }
            }
        }
    }
}

// ---------------- final row-dot + sigmoid ----------------

__global__ void k_final(const float* __restrict__ h2, const float* __restrict__ W3,
                        const float* __restrict__ b3, float* __restrict__ out) {
    int w = (int)((blockIdx.x * 256 + threadIdx.x) >> 6);
    if (w >= NN) return;
    int lane = threadIdx.x & 63;
    float4 h = *(const float4*)(h2 + (size_t)w * 256 + lane * 4);
    float4 ww = *(const float4*)(W3 + lane * 4);
    float p = h.x * ww.x + h.y * ww.y + h.z * ww.z + h.w * ww.w;
    p += __shfl_xor(p, 1);
    p += __shfl_xor(p, 2);
    p += __shfl_xor(p, 4);
    p += __shfl_xor(p, 8);
    p += __shfl_xor(p, 16);
    p += __shfl_xor(p, 32);
    if (lane == 0) out[w] = 1.f / (1.f + __expf(-(p + b3[0])));
}

// sentinel: written iff ws_size is too small (diagnosable absmax ~= 0.5, no crash)
__global__ void k_sent(float* __restrict__ out) {
    int i = blockIdx.x * 256 + threadIdx.x;
    if (i < NN) out[i] = 0.5f;
}

// ---------------- launch ----------------

extern "C" void kernel_launch(void* const* d_in, const int* in_sizes, int n_in,
                              void* d_out, int out_size, void* d_ws, size_t ws_size,
                              hipStream_t stream) {
    const float* features = (const float*)d_in[0];
    const int* src = (const int*)d_in[1];
    const int* dst = (const int*)d_in[2];
    const float* Wm = (const float*)d_in[4];
    const float* bm = (const float*)d_in[5];
    const float* W1 = (const float*)d_in[24];
    const float* b1 = (const float*)d_in[25];
    const float* W2 = (const float*)d_in[26];
    const float* b2 = (const float*)d_in[27];
    const float* W3 = (const float*)d_in[28];
    const float* b3 = (const float*)d_in[29];
    float* out = (float*)d_out;

    char* ws = (char*)d_ws;
    size_t off = 0;
    auto alloc = [&](size_t b) -> void* {
        void* p = ws + off;
        off = (off + b + 255) & ~(size_t)255;
        return p;
    };

    int* deg_o = (int*)alloc(NN * 4);
    int* deg_i = (int*)alloc(NN * 4);
    int* row_ptr = (int*)alloc((NN + 1) * 4);
    int* cursor = (int*)alloc(NN * 4);
    int* col_src = (int*)alloc((size_t)NE * 4);
    float* ewt = (float*)alloc((size_t)NE * 4);
    float* ns = (float*)alloc(NN * 4);
    float* nd = (float*)alloc(NN * 4);
    int* incl = (int*)alloc(NN * 4);
    int* bsum = (int*)alloc(NBLK * 4);
    int* boff = (int*)alloc(NBLK * 4);

    unsigned short* Wmt_h = (unsigned short*)alloc(256 * 256 * 2);
    unsigned short* Wmt_l = (unsigned short*)alloc(256 * 256 * 2);
    unsigned short *Wqkvt_h[3], *Wqkvt_l[3];
    for (int l = 0; l < 3; ++l) {
        Wqkvt_h[l] = (unsigned short*)alloc(768 * 256 * 2);
        Wqkvt_l[l] = (unsigned short*)alloc(768 * 256 * 2);
    }
    float* bqkv = (float*)alloc(3 * 768 * 4);
    unsigned short* W1t_h = (unsigned short*)alloc(512 * 768 * 2);
    unsigned short* W1t_l = (unsigned short*)alloc(512 * 768 * 2);
    unsigned short* W2t_h = (unsigned short*)alloc(256 * 512 * 2);
    unsigned short* W2t_l = (unsigned short*)alloc(256 * 512 * 2);

    float* Qbuf = (float*)alloc((size_t)NN * 256 * 4);          // 51.2 MB
    unsigned short* KV = (unsigned short*)alloc((size_t)NN * 512 * 2);  // 51.2 MB (contiguous after Qbuf)
    float* y = (float*)alloc((size_t)NN * 256 * 4);
    float* xcat = (float*)alloc((size_t)NN * 768 * 4);

    float* x0 = Qbuf;       // dead once layer-1 prop has consumed it
    float* h1 = Qbuf;       // spans Qbuf+KV (102.4 MB contiguous); both dead after attn3
    float* h2 = y;          // y dead after layer-3 QKV gemm

    (void)in_sizes; (void)n_in; (void)out_size;

    if (off > ws_size) {
        k_sent<<<(NN + 255) / 256, 256, 0, stream>>>(out);
        return;
    }

    hipMemsetAsync(deg_o, 0, NN * 4, stream);
    hipMemsetAsync(deg_i, 0, NN * 4, stream);
    k_deg<<<(NE + 255) / 256, 256, 0, stream>>>(src, dst, deg_o, deg_i);
    k_norm<<<NBLK, 256, 0, stream>>>(deg_o, deg_i, ns, nd);
    k_scanA<<<NBLK, 256, 0, stream>>>(deg_i, incl, bsum);
    k_scanB<<<1, 256, 0, stream>>>(bsum, boff, row_ptr);
    k_scanC<<<NBLK, 256, 0, stream>>>(deg_i, incl, boff, row_ptr, cursor);
    k_fill<<<(NE + 255) / 256, 256, 0, stream>>>(src, dst, ns, cursor, col_src, ewt);

    k_wsplit<<<(256 * 256 + 255) / 256, 256, 0, stream>>>(Wm, Wmt_h, Wmt_l, 256, 256);
    QkvPtrs qp;
    BiasPtrs bp;
    for (int l = 0; l < 3; ++l) {
        for (int m = 0; m < 3; ++m) {
            qp.w[l * 3 + m] = (const float*)d_in[6 + l * 6 + m * 2];
            bp.b[l * 3 + m] = (const float*)d_in[7 + l * 6 + m * 2];
        }
        qp.h[l] = Wqkvt_h[l];
        qp.l[l] = Wqkvt_l[l];
    }
    bp.dst = bqkv;
    k_wsplit9<<<dim3(256, 9), 256, 0, stream>>>(qp);
    k_bcat<<<9, 256, 0, stream>>>(bp);
    k_wsplit<<<(768 * 512 + 255) / 256, 256, 0, stream>>>(W1, W1t_h, W1t_l, 768, 512);
    k_wsplit<<<(512 * 256 + 255) / 256, 256, 0, stream>>>(W2, W2t_h, W2t_l, 512, 256);

    const int MB = (NN + 127) / 128;  // 391
    dim3 gN256(MB, 2), gN512(MB, 4), gN768(MB, 6);

    // x0 = relu(features @ Wm + bm)   (x0 lives at Qbuf, ld 256)
    k_gemm<0><<<gN256, 256, 0, stream>>>(features, 256, Wmt_h, Wmt_l, bm,
                                         x0, nullptr, 256, 0, NN, 256);

    const float* xin = x0;
    int ldx = 256;
    for (int l = 0; l < 3; ++l) {
        k_prop<<<12500, 256, 0, stream>>>(xin, ldx, row_ptr, col_src, ewt, nd, y);
        k_gemm<1><<<gN768, 256, 0, stream>>>(y, 256, Wqkvt_h[l], Wqkvt_l[l], bqkv + l * 768,
                                             Qbuf, KV, 0, 0, NN, 256);
        k_attn<<<12500, 256, 0, stream>>>(Qbuf, KV, row_ptr, col_src, xcat + 256 * l);
        xin = xcat + 256 * l;
        ldx = 768;
    }

    // MLP head
    k_gemm<0><<<gN512, 256, 0, stream>>>(xcat, 768, W1t_h, W1t_l, b1,
                                         h1, nullptr, 512, 0, NN, 768);
    k_gemm<0><<<gN256, 256, 0, stream>>>(h1, 512, W2t_h, W2t_l, b2,
                                         h2, nullptr, 256, 0, NN, 512);
    k_final<<<12500, 256, 0, stream>>>(h2, W3, b3, out);
}

// Round 5
// 9.377 us; speedup vs baseline: 1.0474x; 1.0474x over previous
//
#include <hip/hip_runtime.h>
#include <stdint.h>

#define NN 50000
#define NE 800000
#define NBLK 196   // ceil(NN/256)

typedef float f32x4 __attribute__((ext_vector_type(4)));
typedef short s16x8 __attribute__((ext_vector_type(8)));

__device__ __forceinline__ float bf2f(unsigned short u) {
    union { unsigned int i; float f; } v; v.i = ((unsigned int)u) << 16; return v.f;
}
__device__ __forceinline__ unsigned short f2bf(float x) {
    union { float f; unsigned int i; } v; v.f = x;
    unsigned int r = v.i + 0x7FFFu + ((v.i >> 16) & 1u);
    return (unsigned short)(r >> 16);
}

// ---------------- graph preprocessing ----------------

__global__ void k_deg(const int* __restrict__ src, const int* __restrict__ dst,
                      int* __restrict__ dego, int* __restrict__ degi) {
    int e = blockIdx.x * 256 + threadIdx.x;
    if (e < NE) {
        atomicAdd(&dego[src[e]], 1);
        atomicAdd(&degi[dst[e]], 1);
    }
}

// parallel exclusive scan of deg_i (3 phases); scanC also computes norms
__global__ void k_scanA(const int* __restrict__ deg, int* __restrict__ incl,
                        int* __restrict__ bsum) {
    __shared__ int sm[256];
    int t = threadIdx.x, i = blockIdx.x * 256 + t;
    int v = (i < NN) ? deg[i] : 0;
    sm[t] = v;
    __syncthreads();
#pragma unroll
    for (int off = 1; off < 256; off <<= 1) {
        int tv = (t >= off) ? sm[t - off] : 0;
        __syncthreads();
        sm[t] += tv;
        __syncthreads();
    }
    if (i < NN) incl[i] = sm[t];
    if (t == 255) bsum[blockIdx.x] = sm[255];
}

__global__ void k_scanB(const int* __restrict__ bsum, int* __restrict__ boff,
                        int* __restrict__ row_ptr) {
    __shared__ int sm[256];
    int t = threadIdx.x;
    int v = (t < NBLK) ? bsum[t] : 0;
    sm[t] = v;
    __syncthreads();
#pragma unroll
    for (int off = 1; off < 256; off <<= 1) {
        int tv = (t >= off) ? sm[t - off] : 0;
        __syncthreads();
        sm[t] += tv;
        __syncthreads();
    }
    if (t < NBLK) boff[t] = sm[t] - v;  // exclusive
    if (t == 255) row_ptr[NN] = sm[255];
}

__global__ void k_scanC(const int* __restrict__ dego, const int* __restrict__ degi,
                        const int* __restrict__ incl, const int* __restrict__ boff,
                        int* __restrict__ row_ptr, int* __restrict__ cursor,
                        float* __restrict__ ns, float* __restrict__ nd) {
    int i = blockIdx.x * 256 + threadIdx.x;
    if (i < NN) {
        int ex = boff[blockIdx.x] + incl[i] - degi[i];
        row_ptr[i] = ex;
        cursor[i] = ex;
        ns[i] = dego[i] > 0 ? rsqrtf((float)dego[i]) : 0.f;
        nd[i] = degi[i] > 0 ? rsqrtf((float)degi[i]) : 0.f;
    }
}

// fill CSR columns; also emit per-edge weight ewt = ns[src]
__global__ void k_fill(const int* __restrict__ src, const int* __restrict__ dst,
                       const float* __restrict__ ns,
                       int* __restrict__ cursor, int* __restrict__ col_src,
                       float* __restrict__ ewt) {
    int e = blockIdx.x * 256 + threadIdx.x;
    if (e < NE) {
        int s = src[e];
        int slot = atomicAdd(&cursor[dst[e]], 1);
        col_src[slot] = s;
        ewt[slot] = ns[s];
    }
}

// ---------------- weight prep ----------------
// 9 QKV mats [256,256] -> merged hi/lo B^T [768][256] per layer; block 0 of each
// matrix also concats its bias into bdst[3][768].
struct QkvPtrs {
    const float* w[9];
    const float* b[9];
    unsigned short* h[3];
    unsigned short* l[3];
    float* bdst;
};

__global__ void k_wsplit9(QkvPtrs P) {
    int m = blockIdx.y;               // 0..8
    int layer = m / 3, which = m - layer * 3;
    int idx = blockIdx.x * 256 + threadIdx.x;   // 0..65535
    int n = idx >> 8, k = idx & 255;
    float w = P.w[m][(size_t)k * 256 + n];
    unsigned short h = f2bf(w);
    size_t o = (size_t)(which * 256 + n) * 256 + k;
    P.h[layer][o] = h;
    P.l[layer][o] = f2bf(w - bf2f(h));
    if (blockIdx.x == 0)
        P.bdst[layer * 768 + which * 256 + (int)threadIdx.x] = P.b[m][threadIdx.x];
}

// Wm [256,256] / W1 [768,512] / W2 [512,256] -> hi/lo B^T, one dispatch.
struct W3Ptrs { const float* w[3]; unsigned short* h[3]; unsigned short* l[3]; };

__global__ void k_wsplit3(W3Ptrs P) {
    int y = blockIdx.y;               // 0..8: 1 unit Wm, 6 units W1, 2 units W2
    int mi, K, N, sub;
    if (y == 0)      { mi = 0; K = 256; N = 256; sub = 0; }
    else if (y < 7)  { mi = 1; K = 768; N = 512; sub = y - 1; }
    else             { mi = 2; K = 512; N = 256; sub = y - 7; }
    int idx = sub * 65536 + blockIdx.x * 256 + (int)threadIdx.x;
    int n = idx / K, k = idx - n * K;
    float w = P.w[mi][(size_t)k * N + n];
    unsigned short h = f2bf(w);
    P.h[mi][idx] = h;
    P.l[mi][idx] = f2bf(w - bf2f(h));
}

// ---------------- GCN propagate: y[d] = nd[d] * sum ewt[e] * x[src[e]] ----------------
// x is bf16 [NN,256]. One wave per node; lane owns 4 cols (8B loads).

__global__ void k_prop(const unsigned short* __restrict__ xb,
                       const int* __restrict__ row_ptr, const int* __restrict__ col_src,
                       const float* __restrict__ ewt, const float* __restrict__ ndv,
                       float* __restrict__ y) {
    int w = (int)((blockIdx.x * 256 + threadIdx.x) >> 6);
    if (w >= NN) return;
    int lane = threadIdx.x & 63;
    int c = lane * 4;
    float a0 = 0, a1 = 0, a2 = 0, a3 = 0;
    int e0 = row_ptr[w], e1 = row_ptr[w + 1];
    int sv = (e0 < e1) ? col_src[e0] : 0;
    for (int p = e0; p < e1; ++p) {
        int sn = (p + 1 < e1) ? col_src[p + 1] : 0;
        float wv = ewt[p];
        const ushort4 xv = *(const ushort4*)(xb + (size_t)sv * 256 + c);
        a0 += wv * bf2f(xv.x); a1 += wv * bf2f(xv.y);
        a2 += wv * bf2f(xv.z); a3 += wv * bf2f(xv.w);
        sv = sn;
    }
    float sc = ndv[w];
    float4 o; o.x = a0 * sc; o.y = a1 * sc; o.z = a2 * sc; o.w = a3 * sc;
    *(float4*)(y + (size_t)w * 256 + c) = o;
}

// ---------------- edge attention ----------------
// Q [NN,256] fp32; KV [NN,512] bf16 (K then V). One wave per dst node.
// Writes fp32 slice into xcat (for MLP head) and bf16 xprop (next layer's prop).

__global__ void k_attn(const float* __restrict__ Qbuf, const unsigned short* __restrict__ KV,
                       const int* __restrict__ row_ptr, const int* __restrict__ col_src,
                       float* __restrict__ xo, unsigned short* __restrict__ xprop) {
    int w = (int)((blockIdx.x * 256 + threadIdx.x) >> 6);
    if (w >= NN) return;
    int lane = threadIdx.x & 63;
    int c = lane * 4;
    const float4 q = *(const float4*)(Qbuf + (size_t)w * 256 + c);
    float v0 = 0, v1 = 0, v2 = 0, v3 = 0, z = 0;
    int e0 = row_ptr[w], e1 = row_ptr[w + 1];
    int sv = (e0 < e1) ? col_src[e0] : 0;
    for (int p = e0; p < e1; ++p) {
        int sn = (p + 1 < e1) ? col_src[p + 1] : 0;
        const ushort4 ku = *(const ushort4*)(KV + (size_t)sv * 512 + c);
        const ushort4 vu = *(const ushort4*)(KV + (size_t)sv * 512 + 256 + c);
        float t = q.x * bf2f(ku.x) + q.y * bf2f(ku.y) + q.z * bf2f(ku.z) + q.w * bf2f(ku.w);
        t += __shfl_xor(t, 1);
        t += __shfl_xor(t, 2);
        t += __shfl_xor(t, 4);
        t += __shfl_xor(t, 8);
        float scv = __expf(fminf(fmaxf(t * 0.125f, -10.f), 10.f));
        v0 += scv * bf2f(vu.x); v1 += scv * bf2f(vu.y);
        v2 += scv * bf2f(vu.z); v3 += scv * bf2f(vu.w);
        z += scv;
        sv = sn;
    }
    float inv = 1.f / (z + 1e-6f);
    float4 o; o.x = v0 * inv; o.y = v1 * inv; o.z = v2 * inv; o.w = v3 * inv;
    *(float4*)(xo + (size_t)w * 768 + c) = o;
    if (xprop) {
        ushort4 ob;
        ob.x = f2bf(o.x); ob.y = f2bf(o.y); ob.z = f2bf(o.z); ob.w = f2bf(o.w);
        *(ushort4*)(xprop + (size_t)w * 256 + c) = ob;
    }
}

// ---------------- split-bf16 GEMM: C = relu(A @ W + b) ----------------
// A fp32 [M,K], split hi/lo in registers during staging; B hi/lo bf16 B^T [N,K].
// 3-term MFMA ~ fp32. 128x128 tile, BK=32, 4 waves. NITER bcol tiles per block
// (A panel stays L2-hot across them).
// MODE 0: fp32 C (ldc,coff). MODE 1: cols<256 -> Qf fp32, cols 256.. -> KVb bf16.
// MODE 2: bf16 C [M,256] into KVb.

template <int MODE, int NITER>
__global__ __launch_bounds__(256) void k_gemm(
    const float* __restrict__ A, int lda,
    const unsigned short* __restrict__ Bhi, const unsigned short* __restrict__ Blo,
    const float* __restrict__ bias,
    float* __restrict__ C, unsigned short* __restrict__ KVb,
    int ldc, int coff, int M, int K) {
    __shared__ unsigned short sA[2][128][40];
    __shared__ unsigned short sB[2][128][40];
    const int tid = threadIdx.x;
    const int lane = tid & 63;
    const int wid = tid >> 6;
    const int wm = wid & 1, wn = wid >> 1;
    const int fr = lane & 15, kg = lane >> 4;
    const int brow = blockIdx.x * 128;

    for (int it = 0; it < NITER; ++it) {
        const int bcol = (blockIdx.y * NITER + it) * 128;
        f32x4 acc[4][4] = {};

        for (int k0 = 0; k0 < K; k0 += 32) {
#pragma unroll
            for (int rep = 0; rep < 2; ++rep) {
                int s = tid + rep * 256;
                int row = s >> 2, ks = (s & 3) * 8;
                int gr = brow + row;
                float4 f0 = make_float4(0, 0, 0, 0), f1 = make_float4(0, 0, 0, 0);
                if (gr < M) {
                    const float4* ap = (const float4*)(A + (size_t)gr * lda + k0 + ks);
                    f0 = ap[0];
                    f1 = ap[1];
                }
                ushort4 h0, h1v, l0, l1v;
                h0.x = f2bf(f0.x); l0.x = f2bf(f0.x - bf2f(h0.x));
                h0.y = f2bf(f0.y); l0.y = f2bf(f0.y - bf2f(h0.y));
                h0.z = f2bf(f0.z); l0.z = f2bf(f0.z - bf2f(h0.z));
                h0.w = f2bf(f0.w); l0.w = f2bf(f0.w - bf2f(h0.w));
                h1v.x = f2bf(f1.x); l1v.x = f2bf(f1.x - bf2f(h1v.x));
                h1v.y = f2bf(f1.y); l1v.y = f2bf(f1.y - bf2f(h1v.y));
                h1v.z = f2bf(f1.z); l1v.z = f2bf(f1.z - bf2f(h1v.z));
                h1v.w = f2bf(f1.w); l1v.w = f2bf(f1.w - bf2f(h1v.w));
                *(ushort4*)&sA[0][row][ks] = h0;
                *(ushort4*)&sA[0][row][ks + 4] = h1v;
                *(ushort4*)&sA[1][row][ks] = l0;
                *(ushort4*)&sA[1][row][ks + 4] = l1v;
                size_t bbase = (size_t)(bcol + row) * K + k0 + ks;
                *(uint4*)&sB[0][row][ks] = *(const uint4*)(Bhi + bbase);
                *(uint4*)&sB[1][row][ks] = *(const uint4*)(Blo + bbase);
            }
            __syncthreads();
            s16x8 ah[4], al[4], bh[4], bl[4];
#pragma unroll
            for (int f = 0; f < 4; ++f) {
                ah[f] = *(const s16x8*)&sA[0][wm * 64 + f * 16 + fr][kg * 8];
                al[f] = *(const s16x8*)&sA[1][wm * 64 + f * 16 + fr][kg * 8];
                bh[f] = *(const s16x8*)&sB[0][wn * 64 + f * 16 + fr][kg * 8];
                bl[f] = *(const s16x8*)&sB[1][wn * 64 + f * 16 + fr][kg * 8];
            }
#pragma unroll
            for (int i = 0; i < 4; ++i)
#pragma unroll
                for (int j = 0; j < 4; ++j) {
                    acc[i][j] = __builtin_amdgcn_mfma_f32_16x16x32_bf16(ah[i], bh[j], acc[i][j], 0, 0, 0);
                    acc[i][j] = __builtin_amdgcn_mfma_f32_16x16x32_bf16(ah[i], bl[j], acc[i][j], 0, 0, 0);
                    acc[i][j] = __builtin_amdgcn_mfma_f32_16x16x32_bf16(al[i], bh[j], acc[i][j], 0, 0, 0);
                }
            __syncthreads();
        }

#pragma unroll
        for (int i = 0; i < 4; ++i) {
#pragma unroll
            for (int j = 0; j < 4; ++j) {
                int colG = bcol + wn * 64 + j * 16 + fr;
                float bb = bias[colG];
#pragma unroll
                for (int r = 0; r < 4; ++r) {
                    int row = brow + wm * 64 + i * 16 + kg * 4 + r;
                    if (row < M) {
                        float v = fmaxf(acc[i][j][r] + bb, 0.f);
                        if (MODE == 0) {
                            C[(size_t)row * ldc + coff + colG] = v;
                        } else if (MODE == 1) {
                            if (colG < 256) C[(size_t)row * 256 + colG] = v;
                            else KVb[(size_t)row * 512 + (colG - 256)] = f2bf(v);
                        } else {
                            KVb[(size_t)row * 256 + colG] = f2bf(v);
                        }
                    }
                }
            }
        }
    }
}

// ---------------- final row-dot + sigmoid ----------------

__global__ void k_final(const float* __restrict__ h2, const float* __restrict__ W3,
                        const float* __restrict__ b3, float* __restrict__ out) {
    int w = (int)((blockIdx.x * 256 + threadIdx.x) >> 6);
    if (w >= NN) return;
    int lane = threadIdx.x & 63;
    float4 h = *(const float4*)(h2 + (size_t)w * 256 + lane * 4);
    float4 ww = *(const float4*)(W3 + lane * 4);
    float p = h.x * ww.x + h.y * ww.y + h.z * ww.z + h.w * ww.w;
    p += __shfl_xor(p, 1);
    p += __shfl_xor(p, 2);
    p += __shfl_xor(p, 4);
    p += __shfl_xor(p, 8);
    p += __shfl_xor(p, 16);
    p += __shfl_xor(p, 32);
    if (lane == 0) out[w] = 1.f / (1.f + __expf(-(p + b3[0])));
}

// sentinel: written iff ws_size too small (diagnosable absmax ~= 0.5, no crash)
__global__ void k_sent(float* __restrict__ out) {
    int i = blockIdx.x * 256 + threadIdx.x;
    if (i < NN) out[i] = 0.5f;
}

// ---------------- launch ----------------

extern "C" void kernel_launch(void* const* d_in, const int* in_sizes, int n_in,
                              void* d_out, int out_size, void* d_ws, size_t ws_size,
                              hipStream_t stream) {
    const float* features = (const float*)d_in[0];
    const int* src = (const int*)d_in[1];
    const int* dst = (const int*)d_in[2];
    const float* Wm = (const float*)d_in[4];
    const float* bm = (const float*)d_in[5];
    const float* W1 = (const float*)d_in[24];
    const float* b1 = (const float*)d_in[25];
    const float* W2 = (const float*)d_in[26];
    const float* b2 = (const float*)d_in[27];
    const float* W3 = (const float*)d_in[28];
    const float* b3 = (const float*)d_in[29];
    float* out = (float*)d_out;

    char* ws = (char*)d_ws;
    size_t off = 0;
    auto alloc = [&](size_t b) -> void* {
        void* p = ws + off;
        off = (off + b + 255) & ~(size_t)255;
        return p;
    };

    int* deg_o = (int*)alloc(NN * 4);   // deg_o and deg_i adjacent: single memset
    int* deg_i = (int*)alloc(NN * 4);
    int* row_ptr = (int*)alloc((NN + 1) * 4);
    int* cursor = (int*)alloc(NN * 4);
    int* col_src = (int*)alloc((size_t)NE * 4);
    float* ewt = (float*)alloc((size_t)NE * 4);
    float* ns = (float*)alloc(NN * 4);
    float* nd = (float*)alloc(NN * 4);
    int* incl = (int*)alloc(NN * 4);
    int* bsum = (int*)alloc(NBLK * 4);
    int* boff = (int*)alloc(NBLK * 4);

    unsigned short* Wmt_h = (unsigned short*)alloc(256 * 256 * 2);
    unsigned short* Wmt_l = (unsigned short*)alloc(256 * 256 * 2);
    unsigned short *Wqkvt_h[3], *Wqkvt_l[3];
    for (int l = 0; l < 3; ++l) {
        Wqkvt_h[l] = (unsigned short*)alloc(768 * 256 * 2);
        Wqkvt_l[l] = (unsigned short*)alloc(768 * 256 * 2);
    }
    float* bqkv = (float*)alloc(3 * 768 * 4);
    unsigned short* W1t_h = (unsigned short*)alloc(512 * 768 * 2);
    unsigned short* W1t_l = (unsigned short*)alloc(512 * 768 * 2);
    unsigned short* W2t_h = (unsigned short*)alloc(256 * 512 * 2);
    unsigned short* W2t_l = (unsigned short*)alloc(256 * 512 * 2);

    float* Qbuf = (float*)alloc((size_t)NN * 256 * 4);                  // 51.2 MB
    unsigned short* KV = (unsigned short*)alloc((size_t)NN * 512 * 2);  // 51.2 MB (contiguous after Qbuf)
    float* y = (float*)alloc((size_t)NN * 256 * 4);                     // 51.2 MB
    float* xcat = (float*)alloc((size_t)NN * 768 * 4);                  // 153.6 MB
    unsigned short* xprop = (unsigned short*)alloc((size_t)NN * 256 * 2); // 25.6 MB

    unsigned short* x0b = (unsigned short*)xcat;  // dead before attn1 writes xcat
    float* h1 = Qbuf;   // spans Qbuf+KV (contiguous 102.4 MB); dead after attn3
    float* h2 = y;      // y dead after layer-3 QKV gemm

    (void)in_sizes; (void)n_in; (void)out_size;

    if (off > ws_size) {
        k_sent<<<(NN + 255) / 256, 256, 0, stream>>>(out);
        return;
    }

    // one memset covers adjacent deg_o + deg_i
    hipMemsetAsync(deg_o, 0, (size_t)((char*)deg_i - (char*)deg_o) + NN * 4, stream);
    k_deg<<<(NE + 255) / 256, 256, 0, stream>>>(src, dst, deg_o, deg_i);
    k_scanA<<<NBLK, 256, 0, stream>>>(deg_i, incl, bsum);
    k_scanB<<<1, 256, 0, stream>>>(bsum, boff, row_ptr);
    k_scanC<<<NBLK, 256, 0, stream>>>(deg_o, deg_i, incl, boff, row_ptr, cursor, ns, nd);
    k_fill<<<(NE + 255) / 256, 256, 0, stream>>>(src, dst, ns, cursor, col_src, ewt);

    QkvPtrs qp;
    for (int l = 0; l < 3; ++l) {
        for (int m = 0; m < 3; ++m) {
            qp.w[l * 3 + m] = (const float*)d_in[6 + l * 6 + m * 2];
            qp.b[l * 3 + m] = (const float*)d_in[7 + l * 6 + m * 2];
        }
        qp.h[l] = Wqkvt_h[l];
        qp.l[l] = Wqkvt_l[l];
    }
    qp.bdst = bqkv;
    k_wsplit9<<<dim3(256, 9), 256, 0, stream>>>(qp);

    W3Ptrs wp;
    wp.w[0] = Wm; wp.h[0] = Wmt_h; wp.l[0] = Wmt_l;
    wp.w[1] = W1; wp.h[1] = W1t_h; wp.l[1] = W1t_l;
    wp.w[2] = W2; wp.h[2] = W2t_h; wp.l[2] = W2t_l;
    k_wsplit3<<<dim3(256, 9), 256, 0, stream>>>(wp);

    const int MB = (NN + 127) / 128;  // 391
    dim3 g2(MB, 2);

    // x0b = bf16(relu(features @ Wm + bm))
    k_gemm<2, 1><<<g2, 256, 0, stream>>>(features, 256, Wmt_h, Wmt_l, bm,
                                         nullptr, x0b, 0, 0, NN, 256);

    const unsigned short* xin = x0b;
    for (int l = 0; l < 3; ++l) {
        k_prop<<<12500, 256, 0, stream>>>(xin, row_ptr, col_src, ewt, nd, y);
        k_gemm<1, 3><<<g2, 256, 0, stream>>>(y, 256, Wqkvt_h[l], Wqkvt_l[l], bqkv + l * 768,
                                             Qbuf, KV, 0, 0, NN, 256);
        k_attn<<<12500, 256, 0, stream>>>(Qbuf, KV, row_ptr, col_src, xcat + 256 * l,
                                          l < 2 ? xprop : nullptr);
        xin = xprop;
    }

    // MLP head
    k_gemm<0, 2><<<g2, 256, 0, stream>>>(xcat, 768, W1t_h, W1t_l, b1,
                                         h1, nullptr, 512, 0, NN, 768);
    k_gemm<0, 1><<<g2, 256, 0, stream>>>(h1, 512, W2t_h, W2t_l, b2,
                                         h2, nullptr, 256, 0, NN, 512);
    k_final<<<12500, 256, 0, stream>>>(h2, W3, b3, out);
}